// Round 10
// baseline (2604.860 us; speedup 1.0000x reference)
//
#include <hip/hip_runtime.h>

// ---------------------------------------------------------------------------
// HeteroGNN (2-layer hetero GAT) forward on MI355X — first optimized build.
// f32 in / f32 out (proven round 9). Changes vs round 9:
//  * diagnostics removed
//  * CSR-by-dst built once per relation (hist + scan + scatter)
//  * one-wave-per-dst-row gat_row kernel: computes softmax denom + normalized
//    aggregation + bias in registers, single non-atomic row write. Replaces
//    attw/attnorm/aggregate/biasinit (the ~1GB/dispatch atomic kernels).
// ---------------------------------------------------------------------------

static constexpr int NPn = 150000;
static constexpr int NBn = 250000;
static constexpr int En  = 500000;

__device__ __forceinline__ float lrelu(float x, float s) { return x >= 0.0f ? x : s * x; }

__global__ void fill_kernel(float* out, float val, int n) {
  int i = blockIdx.x * blockDim.x + threadIdx.x;
  if (i < n) out[i] = val;
}

// ---------------- CSR build ----------------
__global__ void zero_int_kernel(int* p, int n) {
  int i = blockIdx.x * blockDim.x + threadIdx.x;
  if (i < n) p[i] = 0;
}

__global__ void hist_kernel(const int* __restrict__ dst, int* __restrict__ cnt, int E) {
  int e = blockIdx.x * blockDim.x + threadIdx.x;
  if (e < E) atomicAdd(&cnt[dst[e]], 1);
}

// inclusive scan per 256-block; block totals to bsum
__global__ void scan1_kernel(const int* __restrict__ cnt, int* __restrict__ incl,
                             int* __restrict__ bsum, int n) {
  __shared__ int s[256];
  int i = blockIdx.x * 256 + threadIdx.x;
  s[threadIdx.x] = (i < n) ? cnt[i] : 0;
  __syncthreads();
  for (int o = 1; o < 256; o <<= 1) {
    int t = (threadIdx.x >= o) ? s[threadIdx.x - o] : 0;
    __syncthreads();
    s[threadIdx.x] += t;
    __syncthreads();
  }
  if (i < n) incl[i] = s[threadIdx.x];
  if (threadIdx.x == 255) bsum[blockIdx.x] = s[255];
}

// exclusive scan of block sums (nb <= ~1024), single thread
__global__ void scan2_kernel(int* bsum, int nb) {
  if (blockIdx.x == 0 && threadIdx.x == 0) {
    int run = 0;
    for (int i = 0; i < nb; ++i) { int v = bsum[i]; bsum[i] = run; run += v; }
  }
}

// exclusive offsets: offs[i] = incl[i] - cnt[i] + bsum[i>>8]
__global__ void scan3_kernel(const int* __restrict__ cnt, int* __restrict__ offs,
                             const int* __restrict__ bsum, int n) {
  int i = blockIdx.x * 256 + threadIdx.x;
  if (i < n) offs[i] = offs[i] - cnt[i] + bsum[i >> 8];
}

__global__ void copy_int_kernel(const int* __restrict__ src, int* __restrict__ dstp, int n) {
  int i = blockIdx.x * blockDim.x + threadIdx.x;
  if (i < n) dstp[i] = src[i];
}

__global__ void scatter_kernel(const int* __restrict__ dst, int* __restrict__ cursor,
                               int* __restrict__ eidx, int E) {
  int e = blockIdx.x * blockDim.x + threadIdx.x;
  if (e < E) { int p = atomicAdd(&cursor[dst[e]], 1); eidx[p] = e; }
}

// ---------------- dense kernels (proven round 9) ----------------
// Y[N,64] = lrelu(X[N,32] @ W[32,64] + b, 0.01)
__global__ void proj_kernel(const float* __restrict__ X, const float* __restrict__ W,
                            const float* __restrict__ b, float* __restrict__ Y, int N) {
  __shared__ __align__(16) float Ws[32 * 64];
  __shared__ float bs[64];
  for (int i = threadIdx.x; i < 32 * 64; i += blockDim.x) Ws[i] = W[i];
  if (threadIdx.x < 64) bs[threadIdx.x] = b[threadIdx.x];
  __syncthreads();
  int row = blockIdx.x * blockDim.x + threadIdx.x;
  if (row >= N) return;
  float x[32];
  const float4* x4 = reinterpret_cast<const float4*>(X + (size_t)row * 32);
#pragma unroll
  for (int k = 0; k < 8; ++k) {
    float4 v = x4[k];
    x[4 * k + 0] = v.x; x[4 * k + 1] = v.y; x[4 * k + 2] = v.z; x[4 * k + 3] = v.w;
  }
  float4* y4 = reinterpret_cast<float4*>(Y + (size_t)row * 64);
#pragma unroll
  for (int cg = 0; cg < 4; ++cg) {
    float acc[16];
#pragma unroll
    for (int c = 0; c < 16; ++c) acc[c] = bs[cg * 16 + c];
#pragma unroll
    for (int k = 0; k < 32; ++k) {
      float xv = x[k];
      const float4* w4 = reinterpret_cast<const float4*>(&Ws[k * 64 + cg * 16]);
#pragma unroll
      for (int q = 0; q < 4; ++q) {
        float4 w = w4[q];
        acc[4 * q + 0] += xv * w.x; acc[4 * q + 1] += xv * w.y;
        acc[4 * q + 2] += xv * w.z; acc[4 * q + 3] += xv * w.w;
      }
    }
#pragma unroll
    for (int q = 0; q < 4; ++q)
      y4[cg * 4 + q] = make_float4(lrelu(acc[4 * q + 0], 0.01f), lrelu(acc[4 * q + 1], 0.01f),
                                   lrelu(acc[4 * q + 2], 0.01f), lrelu(acc[4 * q + 3], 0.01f));
  }
}

// H[N,64] = X[N,64] @ W; S1=H.a1; optional S2. X/H may alias (row-private).
__global__ void hgemm_kernel(const float* X, const float* __restrict__ W,
                             const float* __restrict__ a1, const float* __restrict__ a2,
                             float* H, float* __restrict__ S1,
                             float* __restrict__ S2, int N) {
  __shared__ __align__(16) float Ws[64 * 64];
  __shared__ float a1s[64], a2s[64];
  for (int i = threadIdx.x; i < 64 * 64; i += blockDim.x) Ws[i] = W[i];
  if (threadIdx.x < 64) {
    a1s[threadIdx.x] = a1[threadIdx.x];
    a2s[threadIdx.x] = a2 ? a2[threadIdx.x] : 0.0f;
  }
  __syncthreads();
  int row = blockIdx.x * blockDim.x + threadIdx.x;
  if (row >= N) return;
  float x[64];
  const float4* x4 = reinterpret_cast<const float4*>(X + (size_t)row * 64);
#pragma unroll
  for (int k = 0; k < 16; ++k) {
    float4 v = x4[k];
    x[4 * k + 0] = v.x; x[4 * k + 1] = v.y; x[4 * k + 2] = v.z; x[4 * k + 3] = v.w;
  }
  float4* h4 = reinterpret_cast<float4*>(H + (size_t)row * 64);
  float s1 = 0.0f, s2 = 0.0f;
#pragma unroll
  for (int cg = 0; cg < 4; ++cg) {
    float acc[16];
#pragma unroll
    for (int c = 0; c < 16; ++c) acc[c] = 0.0f;
#pragma unroll
    for (int k = 0; k < 64; ++k) {
      float xv = x[k];
      const float4* w4 = reinterpret_cast<const float4*>(&Ws[k * 64 + cg * 16]);
#pragma unroll
      for (int q = 0; q < 4; ++q) {
        float4 w = w4[q];
        acc[4 * q + 0] += xv * w.x; acc[4 * q + 1] += xv * w.y;
        acc[4 * q + 2] += xv * w.z; acc[4 * q + 3] += xv * w.w;
      }
    }
#pragma unroll
    for (int c = 0; c < 16; ++c) {
      s1 += acc[c] * a1s[cg * 16 + c];
      s2 += acc[c] * a2s[cg * 16 + c];
    }
#pragma unroll
    for (int q = 0; q < 4; ++q)
      h4[cg * 4 + q] = make_float4(acc[4 * q + 0], acc[4 * q + 1], acc[4 * q + 2], acc[4 * q + 3]);
  }
  S1[row] = s1;
  if (S2) S2[row] = s2;
}

__global__ void matvec_kernel(const float* __restrict__ X, const float* __restrict__ v,
                              float* __restrict__ out, int N) {
  __shared__ float vs[64];
  if (threadIdx.x < 64) vs[threadIdx.x] = v[threadIdx.x];
  __syncthreads();
  int i = blockIdx.x * blockDim.x + threadIdx.x;
  if (i >= N) return;
  const float4* x4 = reinterpret_cast<const float4*>(X + (size_t)i * 64);
  float s = 0.0f;
#pragma unroll
  for (int k = 0; k < 16; ++k) {
    float4 u = x4[k];
    s += u.x * vs[4 * k + 0] + u.y * vs[4 * k + 1] + u.z * vs[4 * k + 2] + u.w * vs[4 * k + 3];
  }
  out[i] = s;
}

__global__ void head_kernel(const float* __restrict__ X, const float* __restrict__ w,
                            const float* __restrict__ b, float* __restrict__ out, int N) {
  __shared__ float vs[64];
  if (threadIdx.x < 64) vs[threadIdx.x] = w[threadIdx.x];
  __syncthreads();
  int i = blockIdx.x * blockDim.x + threadIdx.x;
  if (i >= N) return;
  const float4* x4 = reinterpret_cast<const float4*>(X + (size_t)i * 64);
  float s = b[0];
#pragma unroll
  for (int k = 0; k < 16; ++k) {
    float4 u = x4[k];
    s += u.x * vs[4 * k + 0] + u.y * vs[4 * k + 1] + u.z * vs[4 * k + 2] + u.w * vs[4 * k + 3];
  }
  out[i] = s;
}

__global__ void rowdot64_kernel(const float* __restrict__ M, const float* __restrict__ v,
                                float* __restrict__ out) {
  __shared__ float vs[64];
  vs[threadIdx.x] = v[threadIdx.x];
  __syncthreads();
  float s = 0.0f;
#pragma unroll
  for (int j = 0; j < 64; ++j) s += M[threadIdx.x * 64 + j] * vs[j];
  out[threadIdx.x] = s;
}

__global__ void edge_dots_kernel(const float* __restrict__ EA, const float* __restrict__ We,
                                 const float* __restrict__ be, const float* __restrict__ wa1,
                                 const float* __restrict__ wa2, float* __restrict__ hd1,
                                 float* __restrict__ hd2, int E) {
  __shared__ __align__(16) float Ws[16 * 64];
  __shared__ float bs[64], w1s[64], w2s[64];
  for (int i = threadIdx.x; i < 16 * 64; i += blockDim.x) Ws[i] = We[i];
  if (threadIdx.x < 64) {
    bs[threadIdx.x] = be[threadIdx.x];
    w1s[threadIdx.x] = wa1[threadIdx.x];
    w2s[threadIdx.x] = wa2 ? wa2[threadIdx.x] : 0.0f;
  }
  __syncthreads();
  int e = blockIdx.x * blockDim.x + threadIdx.x;
  if (e >= E) return;
  float x[16];
  const float4* x4 = reinterpret_cast<const float4*>(EA + (size_t)e * 16);
#pragma unroll
  for (int k = 0; k < 4; ++k) {
    float4 v = x4[k];
    x[4 * k + 0] = v.x; x[4 * k + 1] = v.y; x[4 * k + 2] = v.z; x[4 * k + 3] = v.w;
  }
  float d1 = 0.0f, d2 = 0.0f;
#pragma unroll
  for (int jg = 0; jg < 16; ++jg) {
    float4 t = *reinterpret_cast<const float4*>(&bs[jg * 4]);
#pragma unroll
    for (int k = 0; k < 16; ++k) {
      float4 w = *reinterpret_cast<const float4*>(&Ws[k * 64 + jg * 4]);
      t.x += x[k] * w.x; t.y += x[k] * w.y; t.z += x[k] * w.z; t.w += x[k] * w.w;
    }
    t.x = lrelu(t.x, 0.01f); t.y = lrelu(t.y, 0.01f);
    t.z = lrelu(t.z, 0.01f); t.w = lrelu(t.w, 0.01f);
    float4 w1 = *reinterpret_cast<const float4*>(&w1s[jg * 4]);
    float4 w2 = *reinterpret_cast<const float4*>(&w2s[jg * 4]);
    d1 += t.x * w1.x + t.y * w1.y + t.z * w1.z + t.w * w1.w;
    d2 += t.x * w2.x + t.y * w2.y + t.z * w2.z + t.w * w2.w;
  }
  hd1[e] = d1;
  if (hd2) hd2[e] = d2;
}

__global__ void edge_mean_kernel(const float* __restrict__ EA, const float* __restrict__ We,
                                 const float* __restrict__ be, float* __restrict__ sum_out, int E) {
  __shared__ float Ws[16 * 64];
  __shared__ float bs[64];
  __shared__ float eas[64 * 16];
  __shared__ float partial[256];
  for (int i = threadIdx.x; i < 16 * 64; i += blockDim.x) Ws[i] = We[i];
  if (threadIdx.x < 64) bs[threadIdx.x] = be[threadIdx.x];
  int j = threadIdx.x & 63, q = threadIdx.x >> 6;
  float acc = 0.0f;
  for (int base = blockIdx.x * 64; base < E; base += gridDim.x * 64) {
    int tile = min(64, E - base);
    __syncthreads();
    for (int i = threadIdx.x; i < tile * 16; i += blockDim.x) eas[i] = EA[(size_t)base * 16 + i];
    __syncthreads();
    for (int e = q; e < tile; e += 4) {
      float t = bs[j];
#pragma unroll
      for (int k = 0; k < 16; ++k) t += eas[e * 16 + k] * Ws[k * 64 + j];
      acc += lrelu(t, 0.01f);
    }
  }
  partial[threadIdx.x] = acc;
  __syncthreads();
  if (q == 0) {
    float s = partial[j] + partial[64 + j] + partial[128 + j] + partial[192 + j];
    atomicAdd(&sum_out[j], s);
  }
}

__global__ void selfdot_kernel(const float* __restrict__ sum, const float* __restrict__ wa,
                               float invE, float* __restrict__ out) {
  float v = sum[threadIdx.x] * wa[threadIdx.x] * invE;
#pragma unroll
  for (int o = 32; o >= 1; o >>= 1) v += __shfl_down(v, o, 64);
  if (threadIdx.x == 0) out[0] = v;
}

// ---------------- the fused per-row GAT kernel ----------------
// One wave per dst row. Phase A: softmax denom (lane-strided + wave reduce).
// Phase B: normalized gather-accumulate, single row write (no atomics).
// selfhd != nullptr -> homo relation (implicit self loop). accum: += into out.
__global__ void gat_row_kernel(const int* __restrict__ offs, const int* __restrict__ eidx,
                               const int* __restrict__ esrc,
                               const float* __restrict__ ssrc, const float* __restrict__ sdst,
                               const float* __restrict__ hd, const float* __restrict__ selfhd,
                               const float* __restrict__ H, const float* __restrict__ bias,
                               float* __restrict__ out, int N, int accum) {
  int wid = (int)(((size_t)blockIdx.x * blockDim.x + threadIdx.x) >> 6);
  int lane = threadIdx.x & 63;
  if (wid >= N) return;
  int lo = offs[wid], hi = offs[wid + 1];
  float sd = sdst[wid];
  float wself = 0.0f;
  if (selfhd) wself = __expf(lrelu(ssrc[wid] + sd + selfhd[0], 0.2f));
  float part = 0.0f;
  for (int p = lo + lane; p < hi; p += 64) {
    int e = eidx[p];
    part += __expf(lrelu(ssrc[esrc[e]] + sd + hd[e], 0.2f));
  }
#pragma unroll
  for (int o = 32; o >= 1; o >>= 1) part += __shfl_down(part, o, 64);
  float denom = __shfl(part, 0, 64) + wself + 1e-16f;
  float inv = 1.0f / denom;
  float acc = selfhd ? (wself * inv) * H[(size_t)wid * 64 + lane] : 0.0f;
  for (int p = lo; p < hi; ++p) {
    int e = eidx[p];        // uniform across wave -> broadcast loads
    int s = esrc[e];
    float w = __expf(lrelu(ssrc[s] + sd + hd[e], 0.2f));
    acc += (w * inv) * H[(size_t)s * 64 + lane];
  }
  float r = acc + bias[lane];
  size_t o = (size_t)wid * 64 + lane;
  if (accum) out[o] += r;
  else       out[o] = r;
}

extern "C" void kernel_launch(void* const* d_in, const int* in_sizes, int n_in,
                              void* d_out, int out_size, void* d_ws, size_t ws_size,
                              hipStream_t stream) {
  dim3 B(256);
  auto cdiv = [](int a, int b) { return (a + b - 1) / b; };

  bool okmap = (n_in == 58) &&
               in_sizes[0] == NPn * 32 && in_sizes[1] == NBn * 32 &&
               in_sizes[2] == En * 16 && in_sizes[15] == 4096 &&
               in_sizes[17] == 64 && in_sizes[53] == 64 &&
               in_sizes[55] == 2 * En && in_sizes[57] == 2 * En;
  if (!okmap) {
    fill_kernel<<<cdiv(NPn, 256), B, 0, stream>>>((float*)d_out, 1000.0f, NPn);
    return;
  }

  const float* x_p  = (const float*)d_in[0];
  const float* x_b  = (const float*)d_in[1];
  const float* ea_pp = (const float*)d_in[2];
  const float* ea_bb = (const float*)d_in[3];
  const float* ea_bp = (const float*)d_in[4];
  const float* W_node_p = (const float*)d_in[5];
  const float* b_node_p = (const float*)d_in[6];
  const float* W_node_b = (const float*)d_in[7];
  const float* b_node_b = (const float*)d_in[8];
  const float* W_edge_pp = (const float*)d_in[9];
  const float* b_edge_pp = (const float*)d_in[10];
  const float* W_edge_bb = (const float*)d_in[11];
  const float* b_edge_bb = (const float*)d_in[12];
  const float* W_edge_bp = (const float*)d_in[13];
  const float* b_edge_bp = (const float*)d_in[14];
  const float* c1_pp_W = (const float*)d_in[15];
  const float* c1_pp_We = (const float*)d_in[16];
  const float* c1_pp_asrc = (const float*)d_in[17];
  const float* c1_pp_adst = (const float*)d_in[18];
  const float* c1_pp_aedge = (const float*)d_in[19];
  const float* c1_pp_bias = (const float*)d_in[20];
  const float* c1_bb_W = (const float*)d_in[21];
  const float* c1_bb_We = (const float*)d_in[22];
  const float* c1_bb_asrc = (const float*)d_in[23];
  const float* c1_bb_adst = (const float*)d_in[24];
  const float* c1_bb_aedge = (const float*)d_in[25];
  const float* c1_bb_bias = (const float*)d_in[26];
  const float* c1_bp_Wsrc = (const float*)d_in[27];
  const float* c1_bp_Wdst = (const float*)d_in[28];
  const float* c1_bp_We = (const float*)d_in[29];
  const float* c1_bp_asrc = (const float*)d_in[30];
  const float* c1_bp_adst = (const float*)d_in[31];
  const float* c1_bp_aedge = (const float*)d_in[32];
  const float* c1_bp_bias = (const float*)d_in[33];
  const float* c2_pp_W = (const float*)d_in[34];
  const float* c2_pp_We = (const float*)d_in[35];
  const float* c2_pp_asrc = (const float*)d_in[36];
  const float* c2_pp_adst = (const float*)d_in[37];
  const float* c2_pp_aedge = (const float*)d_in[38];
  const float* c2_pp_bias = (const float*)d_in[39];
  const float* c2_bp_Wsrc = (const float*)d_in[46];
  const float* c2_bp_Wdst = (const float*)d_in[47];
  const float* c2_bp_We = (const float*)d_in[48];
  const float* c2_bp_asrc = (const float*)d_in[49];
  const float* c2_bp_adst = (const float*)d_in[50];
  const float* c2_bp_aedge = (const float*)d_in[51];
  const float* c2_bp_bias = (const float*)d_in[52];
  const float* W_out = (const float*)d_in[53];
  const float* b_out = (const float*)d_in[54];
  const int* ei_pp = (const int*)d_in[55];
  const int* ei_bb = (const int*)d_in[56];
  const int* ei_bp = (const int*)d_in[57];

  // ---- workspace layout
  float* ws = (float*)d_ws;
  int* offs_pp = (int*)ws;                   // NPn+1
  int* offs_bp = offs_pp + (NPn + 1);        // NPn+1
  int* offs_bb = offs_bp + (NPn + 1);        // NBn+1
  int* cnt     = offs_bb + (NBn + 1);        // NBn+1 (cnt, then cursor)
  int* bsum    = cnt + (NBn + 1);            // 1040
  int* eidx_pp = bsum + 1040;                // En
  int* eidx_bp = eidx_pp + En;               // En
  int* eidx_bb = eidx_bp + En;               // En
  float* xp    = (float*)(eidx_bb + En);     // NPn*64 (p2 aliases)
  float* p1    = xp + (size_t)NPn * 64;      // NPn*64
  float* b1v   = p1 + (size_t)NPn * 64;      // NBn*64
  float* hbuf  = b1v + (size_t)NBn * 64;     // NBn*64
  float* hd_pp1 = hbuf + (size_t)NBn * 64;   // En x5
  float* hd_pp2 = hd_pp1 + En;
  float* hd_bb1 = hd_pp2 + En;
  float* hd_bp1 = hd_bb1 + En;
  float* hd_bp2 = hd_bp1 + En;
  float* s_src = hd_bp2 + En;                // NBn
  float* s_dst = s_src + NBn;                // NBn
  float* small = s_dst + NBn;                // 1024
  float* p2    = xp;

  const size_t NEED = (size_t)(small + 1024 - ws) * sizeof(float);
  if (ws_size < NEED) {
    fill_kernel<<<cdiv(NPn, 256), B, 0, stream>>>((float*)d_out, 500.0f, NPn);
    return;
  }

  float* sum_pp  = small + 0;   float* sum_bb  = small + 64;
  float* wa_pp1  = small + 128; float* wa_pp2  = small + 192;
  float* wa_bb1  = small + 256; float* wa_bp1  = small + 320; float* wa_bp2 = small + 384;
  float* wd1     = small + 448; float* wd2     = small + 512;
  float* self_pp1= small + 576; float* self_pp2= small + 577; float* self_bb1 = small + 578;
  const float invE = 1.0f / (float)En;

  hipMemsetAsync(sum_pp, 0, 128 * sizeof(float), stream);

  // ---- projections and edge scalars
  proj_kernel<<<cdiv(NPn, 256), B, 0, stream>>>(x_p, W_node_p, b_node_p, xp, NPn);

  rowdot64_kernel<<<1, 64, 0, stream>>>(c1_pp_We, c1_pp_aedge, wa_pp1);
  rowdot64_kernel<<<1, 64, 0, stream>>>(c2_pp_We, c2_pp_aedge, wa_pp2);
  rowdot64_kernel<<<1, 64, 0, stream>>>(c1_bb_We, c1_bb_aedge, wa_bb1);
  rowdot64_kernel<<<1, 64, 0, stream>>>(c1_bp_We, c1_bp_aedge, wa_bp1);
  rowdot64_kernel<<<1, 64, 0, stream>>>(c2_bp_We, c2_bp_aedge, wa_bp2);
  rowdot64_kernel<<<1, 64, 0, stream>>>(c1_bp_Wdst, c1_bp_adst, wd1);
  rowdot64_kernel<<<1, 64, 0, stream>>>(c2_bp_Wdst, c2_bp_adst, wd2);

  edge_dots_kernel<<<cdiv(En, 256), B, 0, stream>>>(ea_pp, W_edge_pp, b_edge_pp, wa_pp1, wa_pp2, hd_pp1, hd_pp2, En);
  edge_dots_kernel<<<cdiv(En, 256), B, 0, stream>>>(ea_bb, W_edge_bb, b_edge_bb, wa_bb1, nullptr, hd_bb1, nullptr, En);
  edge_dots_kernel<<<cdiv(En, 256), B, 0, stream>>>(ea_bp, W_edge_bp, b_edge_bp, wa_bp1, wa_bp2, hd_bp1, hd_bp2, En);

  edge_mean_kernel<<<512, B, 0, stream>>>(ea_pp, W_edge_pp, b_edge_pp, sum_pp, En);
  edge_mean_kernel<<<512, B, 0, stream>>>(ea_bb, W_edge_bb, b_edge_bb, sum_bb, En);
  selfdot_kernel<<<1, 64, 0, stream>>>(sum_pp, wa_pp1, invE, self_pp1);
  selfdot_kernel<<<1, 64, 0, stream>>>(sum_pp, wa_pp2, invE, self_pp2);
  selfdot_kernel<<<1, 64, 0, stream>>>(sum_bb, wa_bb1, invE, self_bb1);

  // ---- CSR builds (dst-sorted edge lists), reused by both layers
  auto build_csr = [&](const int* dstArr, int* offs, int* eidx, int Nn) {
    int n1 = Nn + 1;
    zero_int_kernel<<<cdiv(n1, 256), B, 0, stream>>>(cnt, n1);
    hist_kernel<<<cdiv(En, 256), B, 0, stream>>>(dstArr, cnt, En);
    int nb = cdiv(n1, 256);
    scan1_kernel<<<nb, B, 0, stream>>>(cnt, offs, bsum, n1);
    scan2_kernel<<<1, 64, 0, stream>>>(bsum, nb);
    scan3_kernel<<<nb, B, 0, stream>>>(cnt, offs, bsum, n1);
    copy_int_kernel<<<cdiv(n1, 256), B, 0, stream>>>(offs, cnt, n1);  // cursor
    scatter_kernel<<<cdiv(En, 256), B, 0, stream>>>(dstArr, cnt, eidx, En);
  };
  build_csr(ei_pp + En, offs_pp, eidx_pp, NPn);
  build_csr(ei_bp + En, offs_bp, eidx_bp, NPn);
  build_csr(ei_bb + En, offs_bb, eidx_bb, NBn);

  // ---- conv1 pp (homo) -> p1
  hgemm_kernel<<<cdiv(NPn, 256), B, 0, stream>>>(xp, c1_pp_W, c1_pp_asrc, c1_pp_adst, hbuf, s_src, s_dst, NPn);
  gat_row_kernel<<<cdiv(NPn * 64, 256), B, 0, stream>>>(offs_pp, eidx_pp, ei_pp, s_src, s_dst,
      hd_pp1, self_pp1, hbuf, c1_pp_bias, p1, NPn, 0);

  // ---- conv1 bp (bipartite b->p) -> p1 (+=)
  proj_kernel<<<cdiv(NBn, 256), B, 0, stream>>>(x_b, W_node_b, b_node_b, hbuf, NBn);
  hgemm_kernel<<<cdiv(NBn, 256), B, 0, stream>>>(hbuf, c1_bp_Wsrc, c1_bp_asrc, nullptr, hbuf, s_src, nullptr, NBn);
  matvec_kernel<<<cdiv(NPn, 256), B, 0, stream>>>(xp, wd1, s_dst, NPn);
  gat_row_kernel<<<cdiv(NPn * 64, 256), B, 0, stream>>>(offs_bp, eidx_bp, ei_bp, s_src, s_dst,
      hd_bp1, nullptr, hbuf, c1_bp_bias, p1, NPn, 1);

  // ---- conv1 bb (homo) -> b1v
  proj_kernel<<<cdiv(NBn, 256), B, 0, stream>>>(x_b, W_node_b, b_node_b, hbuf, NBn);
  hgemm_kernel<<<cdiv(NBn, 256), B, 0, stream>>>(hbuf, c1_bb_W, c1_bb_asrc, c1_bb_adst, hbuf, s_src, s_dst, NBn);
  gat_row_kernel<<<cdiv(NBn * 64, 256), B, 0, stream>>>(offs_bb, eidx_bb, ei_bb, s_src, s_dst,
      hd_bb1, self_bb1, hbuf, c1_bb_bias, b1v, NBn, 0);

  // ---- conv2 pp (homo, input p1) -> p2
  hgemm_kernel<<<cdiv(NPn, 256), B, 0, stream>>>(p1, c2_pp_W, c2_pp_asrc, c2_pp_adst, hbuf, s_src, s_dst, NPn);
  gat_row_kernel<<<cdiv(NPn * 64, 256), B, 0, stream>>>(offs_pp, eidx_pp, ei_pp, s_src, s_dst,
      hd_pp2, self_pp2, hbuf, c2_pp_bias, p2, NPn, 0);

  // ---- conv2 bp (bipartite, src b1v) -> p2 (+=)
  hgemm_kernel<<<cdiv(NBn, 256), B, 0, stream>>>(b1v, c2_bp_Wsrc, c2_bp_asrc, nullptr, hbuf, s_src, nullptr, NBn);
  matvec_kernel<<<cdiv(NPn, 256), B, 0, stream>>>(p1, wd2, s_dst, NPn);
  gat_row_kernel<<<cdiv(NPn * 64, 256), B, 0, stream>>>(offs_bp, eidx_bp, ei_bp, s_src, s_dst,
      hd_bp2, nullptr, hbuf, c2_bp_bias, p2, NPn, 1);

  // ---- head
  head_kernel<<<cdiv(NPn, 256), B, 0, stream>>>(p2, W_out, b_out, (float*)d_out, NPn);
}

// Round 11
// 2268.779 us; speedup vs baseline: 1.1481x; 1.1481x over previous
//
#include <hip/hip_runtime.h>

// ---------------------------------------------------------------------------
// HeteroGNN (2-layer hetero GAT) forward on MI355X — round 11.
// vs round 10 (passed, 2604us): launch count 55 -> ~29 (batched rowdot/
// edge_dots/selfdot, 3-relation CSR build in 7 launches), and gat_row is now
// SINGLE-PASS (unnormalized accumulate, divide at end) — halves the serial
// per-edge work and removes the wave reduce.
// ---------------------------------------------------------------------------

static constexpr int NPn = 150000;
static constexpr int NBn = 250000;
static constexpr int En  = 500000;

// concatenated CSR layout (256-aligned segments)
static constexpr int OFF_PP = 0;
static constexpr int OFF_BP = 150016;   // ceil(150001/256)*256
static constexpr int OFF_BB = 300032;
static constexpr int NCAT   = 550144;   // + ceil(250001/256)*256
static constexpr int NB_TOT = NCAT / 256;  // 2149
static constexpr int BS_BP  = OFF_BP / 256;  // 586
static constexpr int BS_BB  = OFF_BB / 256;  // 1172

__device__ __forceinline__ float lrelu(float x, float s) { return x >= 0.0f ? x : s * x; }

__global__ void fill_kernel(float* out, float val, int n) {
  int i = blockIdx.x * blockDim.x + threadIdx.x;
  if (i < n) out[i] = val;
}

// ---------------- batched CSR build (3 relations) ----------------
struct Dsts { const int* d[3]; };

__global__ void zero_int_kernel(int* p, int n) {
  int i = blockIdx.x * blockDim.x + threadIdx.x;
  if (i < n) p[i] = 0;
}

__global__ void hist_all_kernel(Dsts ds, int* __restrict__ cnt) {
  int t = blockIdx.x * blockDim.x + threadIdx.x;
  if (t >= 3 * En) return;
  int rel = t / En, e = t - rel * En;
  int base = (rel == 0) ? OFF_PP : (rel == 1) ? OFF_BP : OFF_BB;
  atomicAdd(&cnt[base + ds.d[rel][e]], 1);
}

// inclusive scan per 256-block; block totals to bsum  (works on concat array)
__global__ void scan1_kernel(const int* __restrict__ cnt, int* __restrict__ incl,
                             int* __restrict__ bsum, int n) {
  __shared__ int s[256];
  int i = blockIdx.x * 256 + threadIdx.x;
  s[threadIdx.x] = (i < n) ? cnt[i] : 0;
  __syncthreads();
  for (int o = 1; o < 256; o <<= 1) {
    int t = (threadIdx.x >= o) ? s[threadIdx.x - o] : 0;
    __syncthreads();
    s[threadIdx.x] += t;
    __syncthreads();
  }
  if (i < n) incl[i] = s[threadIdx.x];
  if (threadIdx.x == 255) bsum[blockIdx.x] = s[255];
}

// exclusive scan of block sums, one segment per thread (3 segments)
__global__ void scan2_kernel(int* bsum) {
  int t = threadIdx.x;
  if (t >= 3) return;
  int lo = (t == 0) ? 0 : (t == 1) ? BS_BP : BS_BB;
  int hi = (t == 0) ? BS_BP : (t == 1) ? BS_BB : NB_TOT;
  int run = 0;
  for (int i = lo; i < hi; ++i) { int v = bsum[i]; bsum[i] = run; run += v; }
}

__global__ void scan3_kernel(const int* __restrict__ cnt, int* __restrict__ offs,
                             const int* __restrict__ bsum, int n) {
  int i = blockIdx.x * 256 + threadIdx.x;
  if (i < n) offs[i] = offs[i] - cnt[i] + bsum[i >> 8];
}

__global__ void copy_int_kernel(const int* __restrict__ src, int* __restrict__ dstp, int n) {
  int i = blockIdx.x * blockDim.x + threadIdx.x;
  if (i < n) dstp[i] = src[i];
}

__global__ void scatter_all_kernel(Dsts ds, int* __restrict__ cursor, int* __restrict__ eidx) {
  int t = blockIdx.x * blockDim.x + threadIdx.x;
  if (t >= 3 * En) return;
  int rel = t / En, e = t - rel * En;
  int base = (rel == 0) ? OFF_PP : (rel == 1) ? OFF_BP : OFF_BB;
  int p = atomicAdd(&cursor[base + ds.d[rel][e]], 1);
  eidx[rel * En + p] = e;
}

// ---------------- dense kernels (proven) ----------------
__global__ void proj_kernel(const float* __restrict__ X, const float* __restrict__ W,
                            const float* __restrict__ b, float* __restrict__ Y, int N) {
  __shared__ __align__(16) float Ws[32 * 64];
  __shared__ float bs[64];
  for (int i = threadIdx.x; i < 32 * 64; i += blockDim.x) Ws[i] = W[i];
  if (threadIdx.x < 64) bs[threadIdx.x] = b[threadIdx.x];
  __syncthreads();
  int row = blockIdx.x * blockDim.x + threadIdx.x;
  if (row >= N) return;
  float x[32];
  const float4* x4 = reinterpret_cast<const float4*>(X + (size_t)row * 32);
#pragma unroll
  for (int k = 0; k < 8; ++k) {
    float4 v = x4[k];
    x[4 * k + 0] = v.x; x[4 * k + 1] = v.y; x[4 * k + 2] = v.z; x[4 * k + 3] = v.w;
  }
  float4* y4 = reinterpret_cast<float4*>(Y + (size_t)row * 64);
#pragma unroll
  for (int cg = 0; cg < 4; ++cg) {
    float acc[16];
#pragma unroll
    for (int c = 0; c < 16; ++c) acc[c] = bs[cg * 16 + c];
#pragma unroll
    for (int k = 0; k < 32; ++k) {
      float xv = x[k];
      const float4* w4 = reinterpret_cast<const float4*>(&Ws[k * 64 + cg * 16]);
#pragma unroll
      for (int q = 0; q < 4; ++q) {
        float4 w = w4[q];
        acc[4 * q + 0] += xv * w.x; acc[4 * q + 1] += xv * w.y;
        acc[4 * q + 2] += xv * w.z; acc[4 * q + 3] += xv * w.w;
      }
    }
#pragma unroll
    for (int q = 0; q < 4; ++q)
      y4[cg * 4 + q] = make_float4(lrelu(acc[4 * q + 0], 0.01f), lrelu(acc[4 * q + 1], 0.01f),
                                   lrelu(acc[4 * q + 2], 0.01f), lrelu(acc[4 * q + 3], 0.01f));
  }
}

// H = X @ W; S1=H.a1; optional S2. X/H may alias (row-private).
__global__ void hgemm_kernel(const float* X, const float* __restrict__ W,
                             const float* __restrict__ a1, const float* __restrict__ a2,
                             float* H, float* __restrict__ S1,
                             float* __restrict__ S2, int N) {
  __shared__ __align__(16) float Ws[64 * 64];
  __shared__ float a1s[64], a2s[64];
  for (int i = threadIdx.x; i < 64 * 64; i += blockDim.x) Ws[i] = W[i];
  if (threadIdx.x < 64) {
    a1s[threadIdx.x] = a1[threadIdx.x];
    a2s[threadIdx.x] = a2 ? a2[threadIdx.x] : 0.0f;
  }
  __syncthreads();
  int row = blockIdx.x * blockDim.x + threadIdx.x;
  if (row >= N) return;
  float x[64];
  const float4* x4 = reinterpret_cast<const float4*>(X + (size_t)row * 64);
#pragma unroll
  for (int k = 0; k < 16; ++k) {
    float4 v = x4[k];
    x[4 * k + 0] = v.x; x[4 * k + 1] = v.y; x[4 * k + 2] = v.z; x[4 * k + 3] = v.w;
  }
  float4* h4 = reinterpret_cast<float4*>(H + (size_t)row * 64);
  float s1 = 0.0f, s2 = 0.0f;
#pragma unroll
  for (int cg = 0; cg < 4; ++cg) {
    float acc[16];
#pragma unroll
    for (int c = 0; c < 16; ++c) acc[c] = 0.0f;
#pragma unroll
    for (int k = 0; k < 64; ++k) {
      float xv = x[k];
      const float4* w4 = reinterpret_cast<const float4*>(&Ws[k * 64 + cg * 16]);
#pragma unroll
      for (int q = 0; q < 4; ++q) {
        float4 w = w4[q];
        acc[4 * q + 0] += xv * w.x; acc[4 * q + 1] += xv * w.y;
        acc[4 * q + 2] += xv * w.z; acc[4 * q + 3] += xv * w.w;
      }
    }
#pragma unroll
    for (int c = 0; c < 16; ++c) {
      s1 += acc[c] * a1s[cg * 16 + c];
      s2 += acc[c] * a2s[cg * 16 + c];
    }
#pragma unroll
    for (int q = 0; q < 4; ++q)
      h4[cg * 4 + q] = make_float4(acc[4 * q + 0], acc[4 * q + 1], acc[4 * q + 2], acc[4 * q + 3]);
  }
  S1[row] = s1;
  if (S2) S2[row] = s2;
}

__global__ void matvec_kernel(const float* __restrict__ X, const float* __restrict__ v,
                              float* __restrict__ out, int N) {
  __shared__ float vs[64];
  if (threadIdx.x < 64) vs[threadIdx.x] = v[threadIdx.x];
  __syncthreads();
  int i = blockIdx.x * blockDim.x + threadIdx.x;
  if (i >= N) return;
  const float4* x4 = reinterpret_cast<const float4*>(X + (size_t)i * 64);
  float s = 0.0f;
#pragma unroll
  for (int k = 0; k < 16; ++k) {
    float4 u = x4[k];
    s += u.x * vs[4 * k + 0] + u.y * vs[4 * k + 1] + u.z * vs[4 * k + 2] + u.w * vs[4 * k + 3];
  }
  out[i] = s;
}

__global__ void head_kernel(const float* __restrict__ X, const float* __restrict__ w,
                            const float* __restrict__ b, float* __restrict__ out, int N) {
  __shared__ float vs[64];
  if (threadIdx.x < 64) vs[threadIdx.x] = w[threadIdx.x];
  __syncthreads();
  int i = blockIdx.x * blockDim.x + threadIdx.x;
  if (i >= N) return;
  const float4* x4 = reinterpret_cast<const float4*>(X + (size_t)i * 64);
  float s = b[0];
#pragma unroll
  for (int k = 0; k < 16; ++k) {
    float4 u = x4[k];
    s += u.x * vs[4 * k + 0] + u.y * vs[4 * k + 1] + u.z * vs[4 * k + 2] + u.w * vs[4 * k + 3];
  }
  out[i] = s;
}

// 7 batched 64x64 row-dots: out[j] = dot(M_j[row,:], v_j)
struct RowdotJobs { const float* M[7]; const float* v[7]; float* out[7]; };
__global__ void rowdot_batch_kernel(RowdotJobs J) {
  __shared__ float vs[64];
  int j = blockIdx.x;
  vs[threadIdx.x] = J.v[j][threadIdx.x];
  __syncthreads();
  float s = 0.0f;
  const float* M = J.M[j];
#pragma unroll
  for (int c = 0; c < 64; ++c) s += M[threadIdx.x * 64 + c] * vs[c];
  J.out[j][threadIdx.x] = s;
}

// 3 batched edge_dots (blockIdx.x / blocks_per_rel selects relation)
struct EdgeJobs {
  const float* EA[3]; const float* We[3]; const float* be[3];
  const float* wa1[3]; const float* wa2[3]; float* hd1[3]; float* hd2[3];
};
__global__ void edge_dots_batch_kernel(EdgeJobs J, int blocksPerRel) {
  int rel = blockIdx.x / blocksPerRel;
  int eb  = blockIdx.x - rel * blocksPerRel;
  __shared__ __align__(16) float Ws[16 * 64];
  __shared__ float bs[64], w1s[64], w2s[64];
  const float* We = J.We[rel];
  for (int i = threadIdx.x; i < 16 * 64; i += blockDim.x) Ws[i] = We[i];
  if (threadIdx.x < 64) {
    bs[threadIdx.x] = J.be[rel][threadIdx.x];
    w1s[threadIdx.x] = J.wa1[rel][threadIdx.x];
    w2s[threadIdx.x] = J.wa2[rel] ? J.wa2[rel][threadIdx.x] : 0.0f;
  }
  __syncthreads();
  int e = eb * blockDim.x + threadIdx.x;
  if (e >= En) return;
  float x[16];
  const float4* x4 = reinterpret_cast<const float4*>(J.EA[rel] + (size_t)e * 16);
#pragma unroll
  for (int k = 0; k < 4; ++k) {
    float4 v = x4[k];
    x[4 * k + 0] = v.x; x[4 * k + 1] = v.y; x[4 * k + 2] = v.z; x[4 * k + 3] = v.w;
  }
  float d1 = 0.0f, d2 = 0.0f;
#pragma unroll
  for (int jg = 0; jg < 16; ++jg) {
    float4 t = *reinterpret_cast<const float4*>(&bs[jg * 4]);
#pragma unroll
    for (int k = 0; k < 16; ++k) {
      float4 w = *reinterpret_cast<const float4*>(&Ws[k * 64 + jg * 4]);
      t.x += x[k] * w.x; t.y += x[k] * w.y; t.z += x[k] * w.z; t.w += x[k] * w.w;
    }
    t.x = lrelu(t.x, 0.01f); t.y = lrelu(t.y, 0.01f);
    t.z = lrelu(t.z, 0.01f); t.w = lrelu(t.w, 0.01f);
    float4 w1 = *reinterpret_cast<const float4*>(&w1s[jg * 4]);
    float4 w2 = *reinterpret_cast<const float4*>(&w2s[jg * 4]);
    d1 += t.x * w1.x + t.y * w1.y + t.z * w1.z + t.w * w1.w;
    d2 += t.x * w2.x + t.y * w2.y + t.z * w2.z + t.w * w2.w;
  }
  J.hd1[rel][e] = d1;
  if (J.hd2[rel]) J.hd2[rel][e] = d2;
}

__global__ void edge_mean_kernel(const float* __restrict__ EA, const float* __restrict__ We,
                                 const float* __restrict__ be, float* __restrict__ sum_out, int E) {
  __shared__ float Ws[16 * 64];
  __shared__ float bs[64];
  __shared__ float eas[64 * 16];
  __shared__ float partial[256];
  for (int i = threadIdx.x; i < 16 * 64; i += blockDim.x) Ws[i] = We[i];
  if (threadIdx.x < 64) bs[threadIdx.x] = be[threadIdx.x];
  int j = threadIdx.x & 63, q = threadIdx.x >> 6;
  float acc = 0.0f;
  for (int base = blockIdx.x * 64; base < E; base += gridDim.x * 64) {
    int tile = min(64, E - base);
    __syncthreads();
    for (int i = threadIdx.x; i < tile * 16; i += blockDim.x) eas[i] = EA[(size_t)base * 16 + i];
    __syncthreads();
    for (int e = q; e < tile; e += 4) {
      float t = bs[j];
#pragma unroll
      for (int k = 0; k < 16; ++k) t += eas[e * 16 + k] * Ws[k * 64 + j];
      acc += lrelu(t, 0.01f);
    }
  }
  partial[threadIdx.x] = acc;
  __syncthreads();
  if (q == 0) {
    float s = partial[j] + partial[64 + j] + partial[128 + j] + partial[192 + j];
    atomicAdd(&sum_out[j], s);
  }
}

// 3 batched self-dot reductions; one wave per job. <<<1,192>>>
struct SelfJobs { const float* sum[3]; const float* wa[3]; float* out[3]; };
__global__ void selfdot_batch_kernel(SelfJobs J, float invE) {
  int job = threadIdx.x >> 6, lane = threadIdx.x & 63;
  float v = J.sum[job][lane] * J.wa[job][lane] * invE;
#pragma unroll
  for (int o = 32; o >= 1; o >>= 1) v += __shfl_down(v, o, 64);
  if (lane == 0) J.out[job][0] = v;
}

// ---------------- single-pass fused per-row GAT ----------------
// out_row = (sum_e w_e*H[src_e] + w_self*H[row]) / (sum_e w_e + w_self + eps) + bias
__global__ void gat_row_kernel(const int* __restrict__ offs, const int* __restrict__ eidx,
                               const int* __restrict__ esrc,
                               const float* __restrict__ ssrc, const float* __restrict__ sdst,
                               const float* __restrict__ hd, const float* __restrict__ selfhd,
                               const float* __restrict__ H, const float* __restrict__ bias,
                               float* __restrict__ out, int N, int accum) {
  int wid = (int)(((size_t)blockIdx.x * blockDim.x + threadIdx.x) >> 6);
  int lane = threadIdx.x & 63;
  if (wid >= N) return;
  int lo = offs[wid], hi = offs[wid + 1];
  float sd = sdst[wid];
  float wsum = 1e-16f;
  float acc = 0.0f;
  if (selfhd) {
    float wself = __expf(lrelu(ssrc[wid] + sd + selfhd[0], 0.2f));
    wsum += wself;
    acc = wself * H[(size_t)wid * 64 + lane];
  }
  for (int p = lo; p < hi; ++p) {
    int e = eidx[p];     // wave-uniform -> broadcast
    int s = esrc[e];
    float w = __expf(lrelu(ssrc[s] + sd + hd[e], 0.2f));
    wsum += w;
    acc += w * H[(size_t)s * 64 + lane];
  }
  float r = acc / wsum + bias[lane];
  size_t o = (size_t)wid * 64 + lane;
  if (accum) out[o] += r;
  else       out[o] = r;
}

extern "C" void kernel_launch(void* const* d_in, const int* in_sizes, int n_in,
                              void* d_out, int out_size, void* d_ws, size_t ws_size,
                              hipStream_t stream) {
  dim3 B(256);
  auto cdiv = [](int a, int b) { return (a + b - 1) / b; };

  bool okmap = (n_in == 58) &&
               in_sizes[0] == NPn * 32 && in_sizes[1] == NBn * 32 &&
               in_sizes[2] == En * 16 && in_sizes[15] == 4096 &&
               in_sizes[17] == 64 && in_sizes[53] == 64 &&
               in_sizes[55] == 2 * En && in_sizes[57] == 2 * En;
  if (!okmap) {
    fill_kernel<<<cdiv(NPn, 256), B, 0, stream>>>((float*)d_out, 1000.0f, NPn);
    return;
  }

  const float* x_p  = (const float*)d_in[0];
  const float* x_b  = (const float*)d_in[1];
  const float* ea_pp = (const float*)d_in[2];
  const float* ea_bb = (const float*)d_in[3];
  const float* ea_bp = (const float*)d_in[4];
  const float* W_node_p = (const float*)d_in[5];
  const float* b_node_p = (const float*)d_in[6];
  const float* W_node_b = (const float*)d_in[7];
  const float* b_node_b = (const float*)d_in[8];
  const float* W_edge_pp = (const float*)d_in[9];
  const float* b_edge_pp = (const float*)d_in[10];
  const float* W_edge_bb = (const float*)d_in[11];
  const float* b_edge_bb = (const float*)d_in[12];
  const float* W_edge_bp = (const float*)d_in[13];
  const float* b_edge_bp = (const float*)d_in[14];
  const float* c1_pp_W = (const float*)d_in[15];
  const float* c1_pp_We = (const float*)d_in[16];
  const float* c1_pp_asrc = (const float*)d_in[17];
  const float* c1_pp_adst = (const float*)d_in[18];
  const float* c1_pp_aedge = (const float*)d_in[19];
  const float* c1_pp_bias = (const float*)d_in[20];
  const float* c1_bb_W = (const float*)d_in[21];
  const float* c1_bb_We = (const float*)d_in[22];
  const float* c1_bb_asrc = (const float*)d_in[23];
  const float* c1_bb_adst = (const float*)d_in[24];
  const float* c1_bb_aedge = (const float*)d_in[25];
  const float* c1_bb_bias = (const float*)d_in[26];
  const float* c1_bp_Wsrc = (const float*)d_in[27];
  const float* c1_bp_Wdst = (const float*)d_in[28];
  const float* c1_bp_We = (const float*)d_in[29];
  const float* c1_bp_asrc = (const float*)d_in[30];
  const float* c1_bp_adst = (const float*)d_in[31];
  const float* c1_bp_aedge = (const float*)d_in[32];
  const float* c1_bp_bias = (const float*)d_in[33];
  const float* c2_pp_W = (const float*)d_in[34];
  const float* c2_pp_We = (const float*)d_in[35];
  const float* c2_pp_asrc = (const float*)d_in[36];
  const float* c2_pp_adst = (const float*)d_in[37];
  const float* c2_pp_aedge = (const float*)d_in[38];
  const float* c2_pp_bias = (const float*)d_in[39];
  const float* c2_bp_Wsrc = (const float*)d_in[46];
  const float* c2_bp_Wdst = (const float*)d_in[47];
  const float* c2_bp_We = (const float*)d_in[48];
  const float* c2_bp_asrc = (const float*)d_in[49];
  const float* c2_bp_adst = (const float*)d_in[50];
  const float* c2_bp_aedge = (const float*)d_in[51];
  const float* c2_bp_bias = (const float*)d_in[52];
  const float* W_out = (const float*)d_in[53];
  const float* b_out = (const float*)d_in[54];
  const int* ei_pp = (const int*)d_in[55];
  const int* ei_bb = (const int*)d_in[56];
  const int* ei_bp = (const int*)d_in[57];

  // ---- workspace layout
  float* ws = (float*)d_ws;
  int* offs_cat = (int*)ws;                  // NCAT
  int* cnt_cat  = offs_cat + NCAT;           // NCAT
  int* bsum     = cnt_cat + NCAT;            // pad 2560
  int* eidx_cat = bsum + 2560;               // 3*En
  float* xp    = (float*)(eidx_cat + 3 * En);// NPn*64 (p2 aliases)
  float* p1    = xp + (size_t)NPn * 64;      // NPn*64
  float* b1v   = p1 + (size_t)NPn * 64;      // NBn*64
  float* hbuf  = b1v + (size_t)NBn * 64;     // NBn*64
  float* hd_pp1 = hbuf + (size_t)NBn * 64;   // En x5
  float* hd_pp2 = hd_pp1 + En;
  float* hd_bb1 = hd_pp2 + En;
  float* hd_bp1 = hd_bb1 + En;
  float* hd_bp2 = hd_bp1 + En;
  float* s_src = hd_bp2 + En;                // NBn
  float* s_dst = s_src + NBn;                // NBn
  float* small = s_dst + NBn;                // 1024
  float* p2    = xp;

  const size_t NEED = (size_t)(small + 1024 - ws) * sizeof(float);
  if (ws_size < NEED) {
    fill_kernel<<<cdiv(NPn, 256), B, 0, stream>>>((float*)d_out, 500.0f, NPn);
    return;
  }

  float* sum_pp  = small + 0;   float* sum_bb  = small + 64;
  float* wa_pp1  = small + 128; float* wa_pp2  = small + 192;
  float* wa_bb1  = small + 256; float* wa_bp1  = small + 320; float* wa_bp2 = small + 384;
  float* wd1     = small + 448; float* wd2     = small + 512;
  float* self_pp1= small + 576; float* self_pp2= small + 577; float* self_bb1 = small + 578;
  const float invE = 1.0f / (float)En;

  hipMemsetAsync(sum_pp, 0, 128 * sizeof(float), stream);

  // ---- projections, collapsed vectors, edge scalars
  proj_kernel<<<cdiv(NPn, 256), B, 0, stream>>>(x_p, W_node_p, b_node_p, xp, NPn);

  RowdotJobs RJ;
  RJ.M[0] = c1_pp_We;  RJ.v[0] = c1_pp_aedge; RJ.out[0] = wa_pp1;
  RJ.M[1] = c2_pp_We;  RJ.v[1] = c2_pp_aedge; RJ.out[1] = wa_pp2;
  RJ.M[2] = c1_bb_We;  RJ.v[2] = c1_bb_aedge; RJ.out[2] = wa_bb1;
  RJ.M[3] = c1_bp_We;  RJ.v[3] = c1_bp_aedge; RJ.out[3] = wa_bp1;
  RJ.M[4] = c2_bp_We;  RJ.v[4] = c2_bp_aedge; RJ.out[4] = wa_bp2;
  RJ.M[5] = c1_bp_Wdst; RJ.v[5] = c1_bp_adst; RJ.out[5] = wd1;
  RJ.M[6] = c2_bp_Wdst; RJ.v[6] = c2_bp_adst; RJ.out[6] = wd2;
  rowdot_batch_kernel<<<7, 64, 0, stream>>>(RJ);

  EdgeJobs EJ;
  EJ.EA[0] = ea_pp; EJ.We[0] = W_edge_pp; EJ.be[0] = b_edge_pp;
  EJ.wa1[0] = wa_pp1; EJ.wa2[0] = wa_pp2; EJ.hd1[0] = hd_pp1; EJ.hd2[0] = hd_pp2;
  EJ.EA[1] = ea_bb; EJ.We[1] = W_edge_bb; EJ.be[1] = b_edge_bb;
  EJ.wa1[1] = wa_bb1; EJ.wa2[1] = nullptr; EJ.hd1[1] = hd_bb1; EJ.hd2[1] = nullptr;
  EJ.EA[2] = ea_bp; EJ.We[2] = W_edge_bp; EJ.be[2] = b_edge_bp;
  EJ.wa1[2] = wa_bp1; EJ.wa2[2] = wa_bp2; EJ.hd1[2] = hd_bp1; EJ.hd2[2] = hd_bp2;
  int bpr = cdiv(En, 256);
  edge_dots_batch_kernel<<<3 * bpr, B, 0, stream>>>(EJ, bpr);

  edge_mean_kernel<<<512, B, 0, stream>>>(ea_pp, W_edge_pp, b_edge_pp, sum_pp, En);
  edge_mean_kernel<<<512, B, 0, stream>>>(ea_bb, W_edge_bb, b_edge_bb, sum_bb, En);
  SelfJobs SJ;
  SJ.sum[0] = sum_pp; SJ.wa[0] = wa_pp1; SJ.out[0] = self_pp1;
  SJ.sum[1] = sum_pp; SJ.wa[1] = wa_pp2; SJ.out[1] = self_pp2;
  SJ.sum[2] = sum_bb; SJ.wa[2] = wa_bb1; SJ.out[2] = self_bb1;
  selfdot_batch_kernel<<<1, 192, 0, stream>>>(SJ, invE);

  // ---- batched CSR build (7 launches for all 3 relations)
  Dsts DS; DS.d[0] = ei_pp + En; DS.d[1] = ei_bp + En; DS.d[2] = ei_bb + En;
  zero_int_kernel<<<cdiv(NCAT, 256), B, 0, stream>>>(cnt_cat, NCAT);
  hist_all_kernel<<<cdiv(3 * En, 256), B, 0, stream>>>(DS, cnt_cat);
  scan1_kernel<<<NB_TOT, B, 0, stream>>>(cnt_cat, offs_cat, bsum, NCAT);
  scan2_kernel<<<1, 64, 0, stream>>>(bsum);
  scan3_kernel<<<NB_TOT, B, 0, stream>>>(cnt_cat, offs_cat, bsum, NCAT);
  copy_int_kernel<<<cdiv(NCAT, 256), B, 0, stream>>>(offs_cat, cnt_cat, NCAT);
  scatter_all_kernel<<<cdiv(3 * En, 256), B, 0, stream>>>(DS, cnt_cat, eidx_cat);

  const int* offs_pp = offs_cat + OFF_PP;
  const int* offs_bp = offs_cat + OFF_BP;
  const int* offs_bb = offs_cat + OFF_BB;
  const int* eidx_pp = eidx_cat;
  const int* eidx_bp = eidx_cat + En;
  const int* eidx_bb = eidx_cat + 2 * En;

  // ---- conv1 pp (homo) -> p1
  hgemm_kernel<<<cdiv(NPn, 256), B, 0, stream>>>(xp, c1_pp_W, c1_pp_asrc, c1_pp_adst, hbuf, s_src, s_dst, NPn);
  gat_row_kernel<<<cdiv(NPn * 64, 256), B, 0, stream>>>(offs_pp, eidx_pp, ei_pp, s_src, s_dst,
      hd_pp1, self_pp1, hbuf, c1_pp_bias, p1, NPn, 0);

  // ---- conv1 bp (b->p) -> p1 (+=)
  proj_kernel<<<cdiv(NBn, 256), B, 0, stream>>>(x_b, W_node_b, b_node_b, hbuf, NBn);
  hgemm_kernel<<<cdiv(NBn, 256), B, 0, stream>>>(hbuf, c1_bp_Wsrc, c1_bp_asrc, nullptr, hbuf, s_src, nullptr, NBn);
  matvec_kernel<<<cdiv(NPn, 256), B, 0, stream>>>(xp, wd1, s_dst, NPn);
  gat_row_kernel<<<cdiv(NPn * 64, 256), B, 0, stream>>>(offs_bp, eidx_bp, ei_bp, s_src, s_dst,
      hd_bp1, nullptr, hbuf, c1_bp_bias, p1, NPn, 1);

  // ---- conv1 bb (homo) -> b1v
  proj_kernel<<<cdiv(NBn, 256), B, 0, stream>>>(x_b, W_node_b, b_node_b, hbuf, NBn);
  hgemm_kernel<<<cdiv(NBn, 256), B, 0, stream>>>(hbuf, c1_bb_W, c1_bb_asrc, c1_bb_adst, hbuf, s_src, s_dst, NBn);
  gat_row_kernel<<<cdiv(NBn * 64, 256), B, 0, stream>>>(offs_bb, eidx_bb, ei_bb, s_src, s_dst,
      hd_bb1, self_bb1, hbuf, c1_bb_bias, b1v, NBn, 0);

  // ---- conv2 pp (homo, input p1) -> p2
  hgemm_kernel<<<cdiv(NPn, 256), B, 0, stream>>>(p1, c2_pp_W, c2_pp_asrc, c2_pp_adst, hbuf, s_src, s_dst, NPn);
  gat_row_kernel<<<cdiv(NPn * 64, 256), B, 0, stream>>>(offs_pp, eidx_pp, ei_pp, s_src, s_dst,
      hd_pp2, self_pp2, hbuf, c2_pp_bias, p2, NPn, 0);

  // ---- conv2 bp (src b1v) -> p2 (+=)
  hgemm_kernel<<<cdiv(NBn, 256), B, 0, stream>>>(b1v, c2_bp_Wsrc, c2_bp_asrc, nullptr, hbuf, s_src, nullptr, NBn);
  matvec_kernel<<<cdiv(NPn, 256), B, 0, stream>>>(p1, wd2, s_dst, NPn);
  gat_row_kernel<<<cdiv(NPn * 64, 256), B, 0, stream>>>(offs_bp, eidx_bp, ei_bp, s_src, s_dst,
      hd_bp2, nullptr, hbuf, c2_bp_bias, p2, NPn, 1);

  // ---- head
  head_kernel<<<cdiv(NPn, 256), B, 0, stream>>>(p2, W_out, b_out, (float*)d_out, NPn);
}

// Round 12
// 1818.974 us; speedup vs baseline: 1.4320x; 1.2473x over previous
//
#include <hip/hip_runtime.h>

// ---------------------------------------------------------------------------
// HeteroGNN (2-layer hetero GAT) forward on MI355X — round 12.
// vs round 11 (passed, 2269us): edge_dots_batch (measured ~637us/replay,
// per-thread-row serial-FMA structure) replaced by COLUMN-PARALLEL
// edge_fused_kernel in edge_mean's proven layout (LDS-staged edge tiles,
// lanes = columns, conflict-free LDS, shuffle-reduce per edge), which also
// absorbs the two edge_mean launches (column sums for self-loop mean).
// Everything else identical to round 11.
// ---------------------------------------------------------------------------

static constexpr int NPn = 150000;
static constexpr int NBn = 250000;
static constexpr int En  = 500000;

// concatenated CSR layout (256-aligned segments)
static constexpr int OFF_PP = 0;
static constexpr int OFF_BP = 150016;
static constexpr int OFF_BB = 300032;
static constexpr int NCAT   = 550144;
static constexpr int NB_TOT = NCAT / 256;
static constexpr int BS_BP  = OFF_BP / 256;
static constexpr int BS_BB  = OFF_BB / 256;

__device__ __forceinline__ float lrelu(float x, float s) { return x >= 0.0f ? x : s * x; }

__global__ void fill_kernel(float* out, float val, int n) {
  int i = blockIdx.x * blockDim.x + threadIdx.x;
  if (i < n) out[i] = val;
}

// ---------------- batched CSR build ----------------
struct Dsts { const int* d[3]; };

__global__ void zero_int_kernel(int* p, int n) {
  int i = blockIdx.x * blockDim.x + threadIdx.x;
  if (i < n) p[i] = 0;
}

__global__ void hist_all_kernel(Dsts ds, int* __restrict__ cnt) {
  int t = blockIdx.x * blockDim.x + threadIdx.x;
  if (t >= 3 * En) return;
  int rel = t / En, e = t - rel * En;
  int base = (rel == 0) ? OFF_PP : (rel == 1) ? OFF_BP : OFF_BB;
  atomicAdd(&cnt[base + ds.d[rel][e]], 1);
}

__global__ void scan1_kernel(const int* __restrict__ cnt, int* __restrict__ incl,
                             int* __restrict__ bsum, int n) {
  __shared__ int s[256];
  int i = blockIdx.x * 256 + threadIdx.x;
  s[threadIdx.x] = (i < n) ? cnt[i] : 0;
  __syncthreads();
  for (int o = 1; o < 256; o <<= 1) {
    int t = (threadIdx.x >= o) ? s[threadIdx.x - o] : 0;
    __syncthreads();
    s[threadIdx.x] += t;
    __syncthreads();
  }
  if (i < n) incl[i] = s[threadIdx.x];
  if (threadIdx.x == 255) bsum[blockIdx.x] = s[255];
}

__global__ void scan2_kernel(int* bsum) {
  int t = threadIdx.x;
  if (t >= 3) return;
  int lo = (t == 0) ? 0 : (t == 1) ? BS_BP : BS_BB;
  int hi = (t == 0) ? BS_BP : (t == 1) ? BS_BB : NB_TOT;
  int run = 0;
  for (int i = lo; i < hi; ++i) { int v = bsum[i]; bsum[i] = run; run += v; }
}

__global__ void scan3_kernel(const int* __restrict__ cnt, int* __restrict__ offs,
                             const int* __restrict__ bsum, int n) {
  int i = blockIdx.x * 256 + threadIdx.x;
  if (i < n) offs[i] = offs[i] - cnt[i] + bsum[i >> 8];
}

__global__ void copy_int_kernel(const int* __restrict__ src, int* __restrict__ dstp, int n) {
  int i = blockIdx.x * blockDim.x + threadIdx.x;
  if (i < n) dstp[i] = src[i];
}

__global__ void scatter_all_kernel(Dsts ds, int* __restrict__ cursor, int* __restrict__ eidx) {
  int t = blockIdx.x * blockDim.x + threadIdx.x;
  if (t >= 3 * En) return;
  int rel = t / En, e = t - rel * En;
  int base = (rel == 0) ? OFF_PP : (rel == 1) ? OFF_BP : OFF_BB;
  int p = atomicAdd(&cursor[base + ds.d[rel][e]], 1);
  eidx[rel * En + p] = e;
}

// ---------------- dense kernels (proven) ----------------
__global__ void proj_kernel(const float* __restrict__ X, const float* __restrict__ W,
                            const float* __restrict__ b, float* __restrict__ Y, int N) {
  __shared__ __align__(16) float Ws[32 * 64];
  __shared__ float bs[64];
  for (int i = threadIdx.x; i < 32 * 64; i += blockDim.x) Ws[i] = W[i];
  if (threadIdx.x < 64) bs[threadIdx.x] = b[threadIdx.x];
  __syncthreads();
  int row = blockIdx.x * blockDim.x + threadIdx.x;
  if (row >= N) return;
  float x[32];
  const float4* x4 = reinterpret_cast<const float4*>(X + (size_t)row * 32);
#pragma unroll
  for (int k = 0; k < 8; ++k) {
    float4 v = x4[k];
    x[4 * k + 0] = v.x; x[4 * k + 1] = v.y; x[4 * k + 2] = v.z; x[4 * k + 3] = v.w;
  }
  float4* y4 = reinterpret_cast<float4*>(Y + (size_t)row * 64);
#pragma unroll
  for (int cg = 0; cg < 4; ++cg) {
    float acc[16];
#pragma unroll
    for (int c = 0; c < 16; ++c) acc[c] = bs[cg * 16 + c];
#pragma unroll
    for (int k = 0; k < 32; ++k) {
      float xv = x[k];
      const float4* w4 = reinterpret_cast<const float4*>(&Ws[k * 64 + cg * 16]);
#pragma unroll
      for (int q = 0; q < 4; ++q) {
        float4 w = w4[q];
        acc[4 * q + 0] += xv * w.x; acc[4 * q + 1] += xv * w.y;
        acc[4 * q + 2] += xv * w.z; acc[4 * q + 3] += xv * w.w;
      }
    }
#pragma unroll
    for (int q = 0; q < 4; ++q)
      y4[cg * 4 + q] = make_float4(lrelu(acc[4 * q + 0], 0.01f), lrelu(acc[4 * q + 1], 0.01f),
                                   lrelu(acc[4 * q + 2], 0.01f), lrelu(acc[4 * q + 3], 0.01f));
  }
}

// H = X @ W; S1=H.a1; optional S2. X/H may alias (row-private).
__global__ void hgemm_kernel(const float* X, const float* __restrict__ W,
                             const float* __restrict__ a1, const float* __restrict__ a2,
                             float* H, float* __restrict__ S1,
                             float* __restrict__ S2, int N) {
  __shared__ __align__(16) float Ws[64 * 64];
  __shared__ float a1s[64], a2s[64];
  for (int i = threadIdx.x; i < 64 * 64; i += blockDim.x) Ws[i] = W[i];
  if (threadIdx.x < 64) {
    a1s[threadIdx.x] = a1[threadIdx.x];
    a2s[threadIdx.x] = a2 ? a2[threadIdx.x] : 0.0f;
  }
  __syncthreads();
  int row = blockIdx.x * blockDim.x + threadIdx.x;
  if (row >= N) return;
  float x[64];
  const float4* x4 = reinterpret_cast<const float4*>(X + (size_t)row * 64);
#pragma unroll
  for (int k = 0; k < 16; ++k) {
    float4 v = x4[k];
    x[4 * k + 0] = v.x; x[4 * k + 1] = v.y; x[4 * k + 2] = v.z; x[4 * k + 3] = v.w;
  }
  float4* h4 = reinterpret_cast<float4*>(H + (size_t)row * 64);
  float s1 = 0.0f, s2 = 0.0f;
#pragma unroll
  for (int cg = 0; cg < 4; ++cg) {
    float acc[16];
#pragma unroll
    for (int c = 0; c < 16; ++c) acc[c] = 0.0f;
#pragma unroll
    for (int k = 0; k < 64; ++k) {
      float xv = x[k];
      const float4* w4 = reinterpret_cast<const float4*>(&Ws[k * 64 + cg * 16]);
#pragma unroll
      for (int q = 0; q < 4; ++q) {
        float4 w = w4[q];
        acc[4 * q + 0] += xv * w.x; acc[4 * q + 1] += xv * w.y;
        acc[4 * q + 2] += xv * w.z; acc[4 * q + 3] += xv * w.w;
      }
    }
#pragma unroll
    for (int c = 0; c < 16; ++c) {
      s1 += acc[c] * a1s[cg * 16 + c];
      s2 += acc[c] * a2s[cg * 16 + c];
    }
#pragma unroll
    for (int q = 0; q < 4; ++q)
      h4[cg * 4 + q] = make_float4(acc[4 * q + 0], acc[4 * q + 1], acc[4 * q + 2], acc[4 * q + 3]);
  }
  S1[row] = s1;
  if (S2) S2[row] = s2;
}

__global__ void matvec_kernel(const float* __restrict__ X, const float* __restrict__ v,
                              float* __restrict__ out, int N) {
  __shared__ float vs[64];
  if (threadIdx.x < 64) vs[threadIdx.x] = v[threadIdx.x];
  __syncthreads();
  int i = blockIdx.x * blockDim.x + threadIdx.x;
  if (i >= N) return;
  const float4* x4 = reinterpret_cast<const float4*>(X + (size_t)i * 64);
  float s = 0.0f;
#pragma unroll
  for (int k = 0; k < 16; ++k) {
    float4 u = x4[k];
    s += u.x * vs[4 * k + 0] + u.y * vs[4 * k + 1] + u.z * vs[4 * k + 2] + u.w * vs[4 * k + 3];
  }
  out[i] = s;
}

__global__ void head_kernel(const float* __restrict__ X, const float* __restrict__ w,
                            const float* __restrict__ b, float* __restrict__ out, int N) {
  __shared__ float vs[64];
  if (threadIdx.x < 64) vs[threadIdx.x] = w[threadIdx.x];
  __syncthreads();
  int i = blockIdx.x * blockDim.x + threadIdx.x;
  if (i >= N) return;
  const float4* x4 = reinterpret_cast<const float4*>(X + (size_t)i * 64);
  float s = b[0];
#pragma unroll
  for (int k = 0; k < 16; ++k) {
    float4 u = x4[k];
    s += u.x * vs[4 * k + 0] + u.y * vs[4 * k + 1] + u.z * vs[4 * k + 2] + u.w * vs[4 * k + 3];
  }
  out[i] = s;
}

struct RowdotJobs { const float* M[7]; const float* v[7]; float* out[7]; };
__global__ void rowdot_batch_kernel(RowdotJobs J) {
  __shared__ float vs[64];
  int j = blockIdx.x;
  vs[threadIdx.x] = J.v[j][threadIdx.x];
  __syncthreads();
  float s = 0.0f;
  const float* M = J.M[j];
#pragma unroll
  for (int c = 0; c < 64; ++c) s += M[threadIdx.x * 64 + c] * vs[c];
  J.out[j][threadIdx.x] = s;
}

// ---------------- column-parallel fused edge kernel ----------------
// For each relation r: hd1[e] = lrelu(ea@We+be)·wa1 (and hd2 with wa2), plus
// column-sums of lrelu(...) for the self-loop mean (rel 0 -> sum_pp, 1 -> sum_bb).
// Layout: 512 blocks/relation, tile = 64 edges staged in LDS; lanes = columns
// (Ws stride-1 conflict-free, ea uniform broadcast); per-edge 64-lane shuffle
// reduce for the dot products.
struct EdgeJobs {
  const float* EA[3]; const float* We[3]; const float* be[3];
  const float* wa1[3]; const float* wa2[3]; float* hd1[3]; float* hd2[3];
};
__global__ void edge_fused_kernel(EdgeJobs J, float* __restrict__ sum_pp,
                                  float* __restrict__ sum_bb) {
  int rel = blockIdx.x >> 9;          // 512 blocks per relation
  int blk = blockIdx.x & 511;
  __shared__ float Ws[16 * 64];
  __shared__ float bs[64], w1s[64], w2s[64];
  __shared__ float eas[64 * 16];
  __shared__ float partial[256];
  const float* We = J.We[rel];
  for (int i = threadIdx.x; i < 16 * 64; i += blockDim.x) Ws[i] = We[i];
  bool has2 = (J.wa2[rel] != nullptr);
  if (threadIdx.x < 64) {
    bs[threadIdx.x] = J.be[rel][threadIdx.x];
    w1s[threadIdx.x] = J.wa1[rel][threadIdx.x];
    w2s[threadIdx.x] = has2 ? J.wa2[rel][threadIdx.x] : 0.0f;
  }
  const float* EA = J.EA[rel];
  float* hd1 = J.hd1[rel];
  float* hd2 = J.hd2[rel];
  int col = threadIdx.x & 63, q = threadIdx.x >> 6;
  float macc = 0.0f;
  for (int base = blk * 64; base < En; base += 512 * 64) {
    int tile = min(64, En - base);
    __syncthreads();
    for (int i = threadIdx.x; i < tile * 16; i += blockDim.x)
      eas[i] = EA[(size_t)base * 16 + i];
    __syncthreads();
    for (int e = q; e < tile; e += 4) {
      float t = bs[col];
#pragma unroll
      for (int k = 0; k < 16; ++k) t += eas[e * 16 + k] * Ws[k * 64 + col];
      float lr = lrelu(t, 0.01f);
      macc += lr;
      float d1 = lr * w1s[col];
      float d2 = has2 ? lr * w2s[col] : 0.0f;
#pragma unroll
      for (int o = 32; o >= 1; o >>= 1) {
        d1 += __shfl_xor(d1, o, 64);
        d2 += __shfl_xor(d2, o, 64);
      }
      if (col == 0) {
        hd1[base + e] = d1;
        if (has2) hd2[base + e] = d2;
      }
    }
  }
  // fold column sums for the self-loop mean (rel 0 -> pp, rel 1 -> bb)
  if (rel < 2) {
    partial[threadIdx.x] = macc;
    __syncthreads();
    if (q == 0) {
      float s = partial[col] + partial[64 + col] + partial[128 + col] + partial[192 + col];
      atomicAdd(rel == 0 ? &sum_pp[col] : &sum_bb[col], s);
    }
  }
}

struct SelfJobs { const float* sum[3]; const float* wa[3]; float* out[3]; };
__global__ void selfdot_batch_kernel(SelfJobs J, float invE) {
  int job = threadIdx.x >> 6, lane = threadIdx.x & 63;
  float v = J.sum[job][lane] * J.wa[job][lane] * invE;
#pragma unroll
  for (int o = 32; o >= 1; o >>= 1) v += __shfl_down(v, o, 64);
  if (lane == 0) J.out[job][0] = v;
}

// ---------------- single-pass fused per-row GAT ----------------
__global__ void gat_row_kernel(const int* __restrict__ offs, const int* __restrict__ eidx,
                               const int* __restrict__ esrc,
                               const float* __restrict__ ssrc, const float* __restrict__ sdst,
                               const float* __restrict__ hd, const float* __restrict__ selfhd,
                               const float* __restrict__ H, const float* __restrict__ bias,
                               float* __restrict__ out, int N, int accum) {
  int wid = (int)(((size_t)blockIdx.x * blockDim.x + threadIdx.x) >> 6);
  int lane = threadIdx.x & 63;
  if (wid >= N) return;
  int lo = offs[wid], hi = offs[wid + 1];
  float sd = sdst[wid];
  float wsum = 1e-16f;
  float acc = 0.0f;
  if (selfhd) {
    float wself = __expf(lrelu(ssrc[wid] + sd + selfhd[0], 0.2f));
    wsum += wself;
    acc = wself * H[(size_t)wid * 64 + lane];
  }
  for (int p = lo; p < hi; ++p) {
    int e = eidx[p];
    int s = esrc[e];
    float w = __expf(lrelu(ssrc[s] + sd + hd[e], 0.2f));
    wsum += w;
    acc += w * H[(size_t)s * 64 + lane];
  }
  float r = acc / wsum + bias[lane];
  size_t o = (size_t)wid * 64 + lane;
  if (accum) out[o] += r;
  else       out[o] = r;
}

extern "C" void kernel_launch(void* const* d_in, const int* in_sizes, int n_in,
                              void* d_out, int out_size, void* d_ws, size_t ws_size,
                              hipStream_t stream) {
  dim3 B(256);
  auto cdiv = [](int a, int b) { return (a + b - 1) / b; };

  bool okmap = (n_in == 58) &&
               in_sizes[0] == NPn * 32 && in_sizes[1] == NBn * 32 &&
               in_sizes[2] == En * 16 && in_sizes[15] == 4096 &&
               in_sizes[17] == 64 && in_sizes[53] == 64 &&
               in_sizes[55] == 2 * En && in_sizes[57] == 2 * En;
  if (!okmap) {
    fill_kernel<<<cdiv(NPn, 256), B, 0, stream>>>((float*)d_out, 1000.0f, NPn);
    return;
  }

  const float* x_p  = (const float*)d_in[0];
  const float* x_b  = (const float*)d_in[1];
  const float* ea_pp = (const float*)d_in[2];
  const float* ea_bb = (const float*)d_in[3];
  const float* ea_bp = (const float*)d_in[4];
  const float* W_node_p = (const float*)d_in[5];
  const float* b_node_p = (const float*)d_in[6];
  const float* W_node_b = (const float*)d_in[7];
  const float* b_node_b = (const float*)d_in[8];
  const float* W_edge_pp = (const float*)d_in[9];
  const float* b_edge_pp = (const float*)d_in[10];
  const float* W_edge_bb = (const float*)d_in[11];
  const float* b_edge_bb = (const float*)d_in[12];
  const float* W_edge_bp = (const float*)d_in[13];
  const float* b_edge_bp = (const float*)d_in[14];
  const float* c1_pp_W = (const float*)d_in[15];
  const float* c1_pp_We = (const float*)d_in[16];
  const float* c1_pp_asrc = (const float*)d_in[17];
  const float* c1_pp_adst = (const float*)d_in[18];
  const float* c1_pp_aedge = (const float*)d_in[19];
  const float* c1_pp_bias = (const float*)d_in[20];
  const float* c1_bb_W = (const float*)d_in[21];
  const float* c1_bb_We = (const float*)d_in[22];
  const float* c1_bb_asrc = (const float*)d_in[23];
  const float* c1_bb_adst = (const float*)d_in[24];
  const float* c1_bb_aedge = (const float*)d_in[25];
  const float* c1_bb_bias = (const float*)d_in[26];
  const float* c1_bp_Wsrc = (const float*)d_in[27];
  const float* c1_bp_Wdst = (const float*)d_in[28];
  const float* c1_bp_We = (const float*)d_in[29];
  const float* c1_bp_asrc = (const float*)d_in[30];
  const float* c1_bp_adst = (const float*)d_in[31];
  const float* c1_bp_aedge = (const float*)d_in[32];
  const float* c1_bp_bias = (const float*)d_in[33];
  const float* c2_pp_W = (const float*)d_in[34];
  const float* c2_pp_We = (const float*)d_in[35];
  const float* c2_pp_asrc = (const float*)d_in[36];
  const float* c2_pp_adst = (const float*)d_in[37];
  const float* c2_pp_aedge = (const float*)d_in[38];
  const float* c2_pp_bias = (const float*)d_in[39];
  const float* c2_bp_Wsrc = (const float*)d_in[46];
  const float* c2_bp_Wdst = (const float*)d_in[47];
  const float* c2_bp_We = (const float*)d_in[48];
  const float* c2_bp_asrc = (const float*)d_in[49];
  const float* c2_bp_adst = (const float*)d_in[50];
  const float* c2_bp_aedge = (const float*)d_in[51];
  const float* c2_bp_bias = (const float*)d_in[52];
  const float* W_out = (const float*)d_in[53];
  const float* b_out = (const float*)d_in[54];
  const int* ei_pp = (const int*)d_in[55];
  const int* ei_bb = (const int*)d_in[56];
  const int* ei_bp = (const int*)d_in[57];

  // ---- workspace layout
  float* ws = (float*)d_ws;
  int* offs_cat = (int*)ws;                  // NCAT
  int* cnt_cat  = offs_cat + NCAT;           // NCAT
  int* bsum     = cnt_cat + NCAT;            // pad 2560
  int* eidx_cat = bsum + 2560;               // 3*En
  float* xp    = (float*)(eidx_cat + 3 * En);// NPn*64 (p2 aliases)
  float* p1    = xp + (size_t)NPn * 64;      // NPn*64
  float* b1v   = p1 + (size_t)NPn * 64;      // NBn*64
  float* hbuf  = b1v + (size_t)NBn * 64;     // NBn*64
  float* hd_pp1 = hbuf + (size_t)NBn * 64;   // En x5
  float* hd_pp2 = hd_pp1 + En;
  float* hd_bb1 = hd_pp2 + En;
  float* hd_bp1 = hd_bb1 + En;
  float* hd_bp2 = hd_bp1 + En;
  float* s_src = hd_bp2 + En;                // NBn
  float* s_dst = s_src + NBn;                // NBn
  float* small = s_dst + NBn;                // 1024
  float* p2    = xp;

  const size_t NEED = (size_t)(small + 1024 - ws) * sizeof(float);
  if (ws_size < NEED) {
    fill_kernel<<<cdiv(NPn, 256), B, 0, stream>>>((float*)d_out, 500.0f, NPn);
    return;
  }

  float* sum_pp  = small + 0;   float* sum_bb  = small + 64;
  float* wa_pp1  = small + 128; float* wa_pp2  = small + 192;
  float* wa_bb1  = small + 256; float* wa_bp1  = small + 320; float* wa_bp2 = small + 384;
  float* wd1     = small + 448; float* wd2     = small + 512;
  float* self_pp1= small + 576; float* self_pp2= small + 577; float* self_bb1 = small + 578;
  const float invE = 1.0f / (float)En;

  hipMemsetAsync(sum_pp, 0, 128 * sizeof(float), stream);

  // ---- projections, collapsed vectors, edge scalars
  proj_kernel<<<cdiv(NPn, 256), B, 0, stream>>>(x_p, W_node_p, b_node_p, xp, NPn);

  RowdotJobs RJ;
  RJ.M[0] = c1_pp_We;  RJ.v[0] = c1_pp_aedge; RJ.out[0] = wa_pp1;
  RJ.M[1] = c2_pp_We;  RJ.v[1] = c2_pp_aedge; RJ.out[1] = wa_pp2;
  RJ.M[2] = c1_bb_We;  RJ.v[2] = c1_bb_aedge; RJ.out[2] = wa_bb1;
  RJ.M[3] = c1_bp_We;  RJ.v[3] = c1_bp_aedge; RJ.out[3] = wa_bp1;
  RJ.M[4] = c2_bp_We;  RJ.v[4] = c2_bp_aedge; RJ.out[4] = wa_bp2;
  RJ.M[5] = c1_bp_Wdst; RJ.v[5] = c1_bp_adst; RJ.out[5] = wd1;
  RJ.M[6] = c2_bp_Wdst; RJ.v[6] = c2_bp_adst; RJ.out[6] = wd2;
  rowdot_batch_kernel<<<7, 64, 0, stream>>>(RJ);

  EdgeJobs EJ;
  EJ.EA[0] = ea_pp; EJ.We[0] = W_edge_pp; EJ.be[0] = b_edge_pp;
  EJ.wa1[0] = wa_pp1; EJ.wa2[0] = wa_pp2; EJ.hd1[0] = hd_pp1; EJ.hd2[0] = hd_pp2;
  EJ.EA[1] = ea_bb; EJ.We[1] = W_edge_bb; EJ.be[1] = b_edge_bb;
  EJ.wa1[1] = wa_bb1; EJ.wa2[1] = nullptr; EJ.hd1[1] = hd_bb1; EJ.hd2[1] = nullptr;
  EJ.EA[2] = ea_bp; EJ.We[2] = W_edge_bp; EJ.be[2] = b_edge_bp;
  EJ.wa1[2] = wa_bp1; EJ.wa2[2] = wa_bp2; EJ.hd1[2] = hd_bp1; EJ.hd2[2] = hd_bp2;
  edge_fused_kernel<<<3 * 512, B, 0, stream>>>(EJ, sum_pp, sum_bb);

  SelfJobs SJ;
  SJ.sum[0] = sum_pp; SJ.wa[0] = wa_pp1; SJ.out[0] = self_pp1;
  SJ.sum[1] = sum_pp; SJ.wa[1] = wa_pp2; SJ.out[1] = self_pp2;
  SJ.sum[2] = sum_bb; SJ.wa[2] = wa_bb1; SJ.out[2] = self_bb1;
  selfdot_batch_kernel<<<1, 192, 0, stream>>>(SJ, invE);

  // ---- batched CSR build
  Dsts DS; DS.d[0] = ei_pp + En; DS.d[1] = ei_bp + En; DS.d[2] = ei_bb + En;
  zero_int_kernel<<<cdiv(NCAT, 256), B, 0, stream>>>(cnt_cat, NCAT);
  hist_all_kernel<<<cdiv(3 * En, 256), B, 0, stream>>>(DS, cnt_cat);
  scan1_kernel<<<NB_TOT, B, 0, stream>>>(cnt_cat, offs_cat, bsum, NCAT);
  scan2_kernel<<<1, 64, 0, stream>>>(bsum);
  scan3_kernel<<<NB_TOT, B, 0, stream>>>(cnt_cat, offs_cat, bsum, NCAT);
  copy_int_kernel<<<cdiv(NCAT, 256), B, 0, stream>>>(offs_cat, cnt_cat, NCAT);
  scatter_all_kernel<<<cdiv(3 * En, 256), B, 0, stream>>>(DS, cnt_cat, eidx_cat);

  const int* offs_pp = offs_cat + OFF_PP;
  const int* offs_bp = offs_cat + OFF_BP;
  const int* offs_bb = offs_cat + OFF_BB;
  const int* eidx_pp = eidx_cat;
  const int* eidx_bp = eidx_cat + En;
  const int* eidx_bb = eidx_cat + 2 * En;

  // ---- conv1 pp (homo) -> p1
  hgemm_kernel<<<cdiv(NPn, 256), B, 0, stream>>>(xp, c1_pp_W, c1_pp_asrc, c1_pp_adst, hbuf, s_src, s_dst, NPn);
  gat_row_kernel<<<cdiv(NPn * 64, 256), B, 0, stream>>>(offs_pp, eidx_pp, ei_pp, s_src, s_dst,
      hd_pp1, self_pp1, hbuf, c1_pp_bias, p1, NPn, 0);

  // ---- conv1 bp (b->p) -> p1 (+=)
  proj_kernel<<<cdiv(NBn, 256), B, 0, stream>>>(x_b, W_node_b, b_node_b, hbuf, NBn);
  hgemm_kernel<<<cdiv(NBn, 256), B, 0, stream>>>(hbuf, c1_bp_Wsrc, c1_bp_asrc, nullptr, hbuf, s_src, nullptr, NBn);
  matvec_kernel<<<cdiv(NPn, 256), B, 0, stream>>>(xp, wd1, s_dst, NPn);
  gat_row_kernel<<<cdiv(NPn * 64, 256), B, 0, stream>>>(offs_bp, eidx_bp, ei_bp, s_src, s_dst,
      hd_bp1, nullptr, hbuf, c1_bp_bias, p1, NPn, 1);

  // ---- conv1 bb (homo) -> b1v
  proj_kernel<<<cdiv(NBn, 256), B, 0, stream>>>(x_b, W_node_b, b_node_b, hbuf, NBn);
  hgemm_kernel<<<cdiv(NBn, 256), B, 0, stream>>>(hbuf, c1_bb_W, c1_bb_asrc, c1_bb_adst, hbuf, s_src, s_dst, NBn);
  gat_row_kernel<<<cdiv(NBn * 64, 256), B, 0, stream>>>(offs_bb, eidx_bb, ei_bb, s_src, s_dst,
      hd_bb1, self_bb1, hbuf, c1_bb_bias, b1v, NBn, 0);

  // ---- conv2 pp (homo, input p1) -> p2
  hgemm_kernel<<<cdiv(NPn, 256), B, 0, stream>>>(p1, c2_pp_W, c2_pp_asrc, c2_pp_adst, hbuf, s_src, s_dst, NPn);
  gat_row_kernel<<<cdiv(NPn * 64, 256), B, 0, stream>>>(offs_pp, eidx_pp, ei_pp, s_src, s_dst,
      hd_pp2, self_pp2, hbuf, c2_pp_bias, p2, NPn, 0);

  // ---- conv2 bp (src b1v) -> p2 (+=)
  hgemm_kernel<<<cdiv(NBn, 256), B, 0, stream>>>(b1v, c2_bp_Wsrc, c2_bp_asrc, nullptr, hbuf, s_src, nullptr, NBn);
  matvec_kernel<<<cdiv(NPn, 256), B, 0, stream>>>(p1, wd2, s_dst, NPn);
  gat_row_kernel<<<cdiv(NPn * 64, 256), B, 0, stream>>>(offs_bp, eidx_bp, ei_bp, s_src, s_dst,
      hd_bp2, nullptr, hbuf, c2_bp_bias, p2, NPn, 1);

  // ---- head
  head_kernel<<<cdiv(NPn, 256), B, 0, stream>>>(p2, W_out, b_out, (float*)d_out, NPn);
}